// Round 7
// baseline (46.069 us; speedup 1.0000x reference)
//
#include <hip/hip_runtime.h>
#include <hip/hip_bf16.h>

// Shapes (from reference setup):
//   x:        (32, 512, 384) float32
//   duration: (32, 512)      int32, values in [0,16)
//   max_len = 4096
// Outputs (concatenated flat in d_out, all read back as float32):
//   out:   (32, 4096, 384) float32   -> d_out[0 .. 50331647]
//   total: (32,)                     -> d_out[50331648 .. 50331679]

#define B      32
#define S      512          // source rows per batch
#define T      4096         // max_len
#define D      384          // feature dim (96 float4)
#define D4     96
#define TILE_T 64           // t-rows per block (2048 blocks, 8/CU, 32 waves/CU)
#define ITERS  ((TILE_T * D4) / 256)   // 24

// Native clang vector for __builtin_nontemporal_store (rejects HIP float4).
typedef float vfloat4 __attribute__((ext_vector_type(4)));

// ---------------------------------------------------------------------------
// R6 base + ONE change: nontemporal stores for `out` (written once, never
// re-read) to stop 201 MB of streaming writes from evicting the 24 MB
// x working set out of L2.
// ---------------------------------------------------------------------------
__global__ __launch_bounds__(256) void lr_fused_kernel(
    const vfloat4* __restrict__ x,       // (B, S, D4)
    const int*    __restrict__ duration, // (B, S)
    vfloat4*      __restrict__ out,      // (B, T, D4)
    float*        __restrict__ total_out)// (B,)
{
    const int blk = blockIdx.x;
    const int b   = blk >> 6;                 // 64 tiles per batch
    const int t0  = (blk & 63) * TILE_T;
    const int tid = threadIdx.x;              // 0..255
    const int lane = tid & 63;
    const int wid  = tid >> 6;                // 0..3

    __shared__ int s_cs[S];                   // inclusive cumsum
    __shared__ int s_wsum[4];                 // per-wave totals
    __shared__ int s_idx[TILE_T];

    // --- local scan of durations (2 elements per thread, shfl wave-scan) ---
    const int2 d2 = ((const int2*)(duration + b * S))[tid];
    const int a1 = max(d2.y, 0);
    int p = max(d2.x, 0) + a1;                // pair sum

    #pragma unroll
    for (int off = 1; off < 64; off <<= 1) {
        int v = __shfl_up(p, off, 64);
        if (lane >= off) p += v;
    }
    if (lane == 63) s_wsum[wid] = p;
    __syncthreads();

    int prefix = 0;
    #pragma unroll
    for (int w = 0; w < 3; ++w) prefix += (w < wid) ? s_wsum[w] : 0;

    const int P = p + prefix;                 // inclusive sum through pair tid
    s_cs[2 * tid]     = P - a1;
    s_cs[2 * tid + 1] = P;
    __syncthreads();

    const int total = s_cs[S - 1];
    if (t0 == 0 && tid == 0) {
        total_out[b] = (float)total;
    }

    // --- per-row source index via branchless upper_bound ---
    if (tid < TILE_T) {
        const int t = t0 + tid;
        int idx = -1;                          // -1 => write zeros
        if (t < total) {
            int lo = 0;                        // lo = #elements cs[j] <= t
            #pragma unroll
            for (int step = 256; step > 0; step >>= 1) {
                int mid = lo + step;
                if (mid <= S && s_cs[mid - 1] <= t) lo = mid;
            }
            idx = min(lo, S - 1);
        }
        s_idx[tid] = idx;
    }
    __syncthreads();

    // --- gather-copy: 64 rows x 96 float4 = 6144 float4 per block ---
    const vfloat4* xb = x   + (size_t)b * S * D4;
    vfloat4*       ob = out + ((size_t)b * T + t0) * D4;

    // Hoist the 24 row indices to registers: batched ds_read, one drain.
    int rows[ITERS];
    #pragma unroll
    for (int i = 0; i < ITERS; ++i) {
        const int e = tid + 256 * i;
        rows[i] = s_idx[e / D4];
    }

    // Pure load/store stream: 24 independent pairs; NT stores keep L2 for x.
    #pragma unroll
    for (int i = 0; i < ITERS; ++i) {
        const int e = tid + 256 * i;
        const int r = e / D4;
        const int c = e - r * D4;
        const int idx = rows[i];
        vfloat4 v;
        if (idx < 0) {
            v = (vfloat4)(0.f);
        } else {
            v = xb[idx * D4 + c];
        }
        __builtin_nontemporal_store(v, &ob[r * D4 + c]);
    }
}

// ---------------------------------------------------------------------------
extern "C" void kernel_launch(void* const* d_in, const int* in_sizes, int n_in,
                              void* d_out, int out_size, void* d_ws, size_t ws_size,
                              hipStream_t stream) {
    const float* x        = (const float*)d_in[0];
    const int*   duration = (const int*)d_in[1];
    // d_in[2] = max_len scalar (=4096), compile-time constant here.

    float* out      = (float*)d_out;
    float* total_of = out + (size_t)B * T * D;   // tail of d_out

    const int nblocks = B * (T / TILE_T);        // 2048
    lr_fused_kernel<<<nblocks, 256, 0, stream>>>(
        (const vfloat4*)x, duration, (vfloat4*)out, total_of);
}

// Round 8
// 40.255 us; speedup vs baseline: 1.1444x; 1.1444x over previous
//
#include <hip/hip_runtime.h>
#include <hip/hip_bf16.h>

// Shapes (from reference setup):
//   x:        (32, 512, 384) float32
//   duration: (32, 512)      int32, values in [0,16)
//   max_len = 4096
// Outputs (concatenated flat in d_out, all read back as float32):
//   out:   (32, 4096, 384) float32   -> d_out[0 .. 50331647]
//   total: (32,)                     -> d_out[50331648 .. 50331679]
//
// Verified-by-A/B design notes (this session):
//  - Fused single kernel beats scan+gather two-kernel by ~4 us (launch+dep).
//  - Plain stores beat __builtin_nontemporal_store by ~5.6 us (L2 write
//    buffering helps the 201 MB write stream; NT bypass hurts).
//  - TILE_T=64 (2048 blocks, 8/CU, 32 waves/CU) beats TILE_T=128 (4/CU).
//  - Shfl-scan vs 17-barrier Hillis-Steele: null (prologues run concurrently
//    across blocks, latency-parallel) — kept for the lower barrier count.
//  - Index-hoist/full-unroll of the gather loop: null (not instr-limited).
//  - Effective 5.6 TB/s on 89%-write mixed traffic ~= mixed-stream HBM
//    ceiling (pure-write fill: 6.9; pure copy ubench: 6.3).

#define B      32
#define S      512          // source rows per batch
#define T      4096         // max_len
#define D      384          // feature dim (96 float4)
#define D4     96
#define TILE_T 64           // t-rows per block (2048 blocks, 8/CU, 32 waves/CU)

__global__ __launch_bounds__(256) void lr_fused_kernel(
    const float4* __restrict__ x,        // (B, S, D4)
    const int*    __restrict__ duration, // (B, S)
    float4*       __restrict__ out,      // (B, T, D4)
    float*        __restrict__ total_out)// (B,)
{
    const int blk = blockIdx.x;
    const int b   = blk >> 6;                 // 64 tiles per batch
    const int t0  = (blk & 63) * TILE_T;
    const int tid = threadIdx.x;              // 0..255
    const int lane = tid & 63;
    const int wid  = tid >> 6;                // 0..3

    __shared__ int s_cs[S];                   // inclusive cumsum
    __shared__ int s_wsum[4];                 // per-wave totals
    __shared__ int s_idx[TILE_T];

    // --- local scan of durations (2 elements per thread, shfl wave-scan) ---
    const int2 d2 = ((const int2*)(duration + b * S))[tid];
    const int a1 = max(d2.y, 0);
    int p = max(d2.x, 0) + a1;                // pair sum

    #pragma unroll
    for (int off = 1; off < 64; off <<= 1) {
        int v = __shfl_up(p, off, 64);
        if (lane >= off) p += v;
    }
    if (lane == 63) s_wsum[wid] = p;
    __syncthreads();

    int prefix = 0;
    #pragma unroll
    for (int w = 0; w < 3; ++w) prefix += (w < wid) ? s_wsum[w] : 0;

    const int P = p + prefix;                 // inclusive sum through pair tid
    s_cs[2 * tid]     = P - a1;
    s_cs[2 * tid + 1] = P;
    __syncthreads();

    const int total = s_cs[S - 1];
    if (t0 == 0 && tid == 0) {
        total_out[b] = (float)total;
    }

    // --- per-row source index via branchless upper_bound ---
    if (tid < TILE_T) {
        const int t = t0 + tid;
        int idx = -1;                          // -1 => write zeros
        if (t < total) {
            int lo = 0;                        // lo = #elements cs[j] <= t
            #pragma unroll
            for (int step = 256; step > 0; step >>= 1) {
                int mid = lo + step;
                if (mid <= S && s_cs[mid - 1] <= t) lo = mid;
            }
            idx = min(lo, S - 1);
        }
        s_idx[tid] = idx;
    }
    __syncthreads();

    // --- gather-copy: 64 rows x 96 float4 = 6144 float4 per block ---
    const float4* xb = x   + (size_t)b * S * D4;
    float4*       ob = out + ((size_t)b * T + t0) * D4;

    #pragma unroll 4
    for (int e = tid; e < TILE_T * D4; e += 256) {
        const int r = e / D4;                 // constant div -> magic mul
        const int c = e - r * D4;
        const int idx = s_idx[r];
        float4 v;
        if (idx < 0) {
            v = make_float4(0.f, 0.f, 0.f, 0.f);
        } else {
            v = xb[idx * D4 + c];
        }
        ob[r * D4 + c] = v;
    }
}

// ---------------------------------------------------------------------------
extern "C" void kernel_launch(void* const* d_in, const int* in_sizes, int n_in,
                              void* d_out, int out_size, void* d_ws, size_t ws_size,
                              hipStream_t stream) {
    const float* x        = (const float*)d_in[0];
    const int*   duration = (const int*)d_in[1];
    // d_in[2] = max_len scalar (=4096), compile-time constant here.

    float* out      = (float*)d_out;
    float* total_of = out + (size_t)B * T * D;   // tail of d_out

    const int nblocks = B * (T / TILE_T);        // 2048
    lr_fused_kernel<<<nblocks, 256, 0, stream>>>(
        (const float4*)x, duration, (float4*)out, total_of);
}